// Round 1
// baseline (604.773 us; speedup 1.0000x reference)
//
#include <hip/hip_runtime.h>

#define N_NODES 100000
#define N_EDGES 1200000
#define NF 64

// ---------------- workspace layout (bytes) ----------------
// deg/dinv : [0, 400128)            int then float, in-place convert
// cnt      : [400128, 800256)       in-degree (non-self) histogram
// offs     : [800256, 1200384)      exclusive scan of cnt
// cursor   : [1200384, 1600512)     fill cursors (= offs copy)
// bsums    : [1600512, 1602560)     block sums for scan (391 used)
// csr      : [1602560, 11202560)    int2{src, norm} per non-self edge
// h        : [11202560, 36802560)   layer-1 output (100000 x 64 f32)
#define OFF_DEG    0
#define OFF_CNT    400128
#define OFF_OFFS   800256
#define OFF_CURSOR 1200384
#define OFF_BSUMS  1600512
#define OFF_CSR    1602560
#define OFF_H      11202560

#define NB1 391   // ceil(100000/256)

__global__ __launch_bounds__(256) void cheb_hist(const int* __restrict__ row,
                                                 const int* __restrict__ col,
                                                 int* __restrict__ deg,
                                                 int* __restrict__ cnt) {
    int e = blockIdx.x * 256 + threadIdx.x;
    if (e < N_EDGES) {
        int s = row[e], d = col[e];
        if (s != d) {
            atomicAdd(&deg[s], 1);
            atomicAdd(&cnt[d], 1);
        }
    }
}

__global__ __launch_bounds__(256) void cheb_dinv(int* __restrict__ deg_io) {
    int i = blockIdx.x * 256 + threadIdx.x;
    if (i < N_NODES) {
        int dg = deg_io[i];
        float v = (dg > 0) ? rsqrtf((float)dg) : 0.0f;
        ((float*)deg_io)[i] = v;
    }
}

// block-wise exclusive scan of cnt -> offs, block totals -> bsums
__global__ __launch_bounds__(256) void cheb_scanA(const int* __restrict__ cnt,
                                                  int* __restrict__ offs,
                                                  int* __restrict__ bsums) {
    __shared__ int s[256];
    int t = threadIdx.x;
    int i = blockIdx.x * 256 + t;
    int v = (i < N_NODES) ? cnt[i] : 0;
    s[t] = v;
    __syncthreads();
    for (int off = 1; off < 256; off <<= 1) {
        int add = (t >= off) ? s[t - off] : 0;
        __syncthreads();
        s[t] += add;
        __syncthreads();
    }
    if (i < N_NODES) offs[i] = s[t] - v;      // exclusive within block
    if (t == 255) bsums[blockIdx.x] = s[255]; // block total
}

// exclusive scan of the 391 block sums (single block)
__global__ __launch_bounds__(512) void cheb_scanB(int* __restrict__ bsums) {
    __shared__ int s[512];
    int t = threadIdx.x;
    int v = (t < NB1) ? bsums[t] : 0;
    s[t] = v;
    __syncthreads();
    for (int off = 1; off < 512; off <<= 1) {
        int add = (t >= off) ? s[t - off] : 0;
        __syncthreads();
        s[t] += add;
        __syncthreads();
    }
    if (t < NB1) bsums[t] = s[t] - v;
}

__global__ __launch_bounds__(256) void cheb_scanC(int* __restrict__ offs,
                                                  const int* __restrict__ bsums,
                                                  int* __restrict__ cursor) {
    int i = blockIdx.x * 256 + threadIdx.x;
    if (i < N_NODES) {
        int o = offs[i] + bsums[blockIdx.x];
        offs[i] = o;
        cursor[i] = o;
    }
}

__global__ __launch_bounds__(256) void cheb_fill(const int* __restrict__ row,
                                                 const int* __restrict__ col,
                                                 const float* __restrict__ dinv,
                                                 int* __restrict__ cursor,
                                                 int2* __restrict__ csr) {
    int e = blockIdx.x * 256 + threadIdx.x;
    if (e < N_EDGES) {
        int s = row[e], d = col[e];
        if (s != d) {
            float nrm = -dinv[s] * dinv[d];
            int idx = atomicAdd(&cursor[d], 1);
            csr[idx] = make_int2(s, __float_as_int(nrm));
        }
    }
}

// Fused: per-node aggregation (Tx1 gather) + GEMM (x@W0 + Tx1@W1 + b) [+relu]
// One wave per node, 8 nodes per wave, 4 waves per block -> 32 nodes/block.
#define NODES_PER_WAVE 8
#define WAVES_PER_BLOCK 4
#define NODES_PER_BLOCK (NODES_PER_WAVE * WAVES_PER_BLOCK)

__global__ __launch_bounds__(256) void cheb_layer(const float* __restrict__ x,
                                                  const int2* __restrict__ csr,
                                                  const int* __restrict__ offs,
                                                  const int* __restrict__ cnt,
                                                  const float* __restrict__ W0,
                                                  const float* __restrict__ W1,
                                                  const float* __restrict__ bias,
                                                  float* __restrict__ out,
                                                  int do_relu) {
    __shared__ float sW0[NF * NF];
    __shared__ float sW1[NF * NF];
    __shared__ float2 sXT[WAVES_PER_BLOCK][NF];

    int t = threadIdx.x;
    for (int i = t; i < NF * NF; i += 256) {
        sW0[i] = W0[i];
        sW1[i] = W1[i];
    }
    __syncthreads();

    int lane = t & 63;
    int wid = t >> 6;
    float bl = bias[lane];
    int base = blockIdx.x * NODES_PER_BLOCK + wid * NODES_PER_WAVE;

    for (int g = 0; g < NODES_PER_WAVE; ++g) {
        int node = base + g;  // grid sized exactly: always < N_NODES
        float xv = x[node * NF + lane];
        int start = __builtin_amdgcn_readfirstlane(offs[node]);
        int cn = __builtin_amdgcn_readfirstlane(cnt[node]);
        float acc = 0.0f;
        for (int e = 0; e < cn; ++e) {
            int2 p = csr[start + e];
            acc = fmaf(__int_as_float(p.y), x[p.x * NF + lane], acc);
        }
        sXT[wid][lane] = make_float2(xv, acc);
        __builtin_amdgcn_wave_barrier();  // wave-internal LDS ordering fence

        float o = bl;
#pragma unroll
        for (int l = 0; l < NF; ++l) {
            float2 p = sXT[wid][l];
            o = fmaf(p.x, sW0[l * NF + lane], o);
            o = fmaf(p.y, sW1[l * NF + lane], o);
        }
        if (do_relu) o = fmaxf(o, 0.0f);
        out[node * NF + lane] = o;
        __builtin_amdgcn_wave_barrier();
    }
}

extern "C" void kernel_launch(void* const* d_in, const int* in_sizes, int n_in,
                              void* d_out, int out_size, void* d_ws, size_t ws_size,
                              hipStream_t stream) {
    const int* ei = (const int*)d_in[0];
    const int* row = ei;
    const int* col = ei + N_EDGES;
    const float* emb = (const float*)d_in[1];
    const float* W1_0 = (const float*)d_in[2];
    const float* W1_1 = (const float*)d_in[3];
    const float* b1 = (const float*)d_in[4];
    const float* W2_0 = (const float*)d_in[5];
    const float* W2_1 = (const float*)d_in[6];
    const float* b2 = (const float*)d_in[7];
    float* out = (float*)d_out;

    char* ws = (char*)d_ws;
    int* deg = (int*)(ws + OFF_DEG);
    int* cnt = (int*)(ws + OFF_CNT);
    int* offs = (int*)(ws + OFF_OFFS);
    int* cursor = (int*)(ws + OFF_CURSOR);
    int* bsums = (int*)(ws + OFF_BSUMS);
    int2* csr = (int2*)(ws + OFF_CSR);
    float* h = (float*)(ws + OFF_H);

    hipMemsetAsync(deg, 0, N_NODES * sizeof(int), stream);
    hipMemsetAsync(cnt, 0, N_NODES * sizeof(int), stream);

    int eb = (N_EDGES + 255) / 256;
    cheb_hist<<<eb, 256, 0, stream>>>(row, col, deg, cnt);
    cheb_dinv<<<NB1, 256, 0, stream>>>(deg);
    cheb_scanA<<<NB1, 256, 0, stream>>>(cnt, offs, bsums);
    cheb_scanB<<<1, 512, 0, stream>>>(bsums);
    cheb_scanC<<<NB1, 256, 0, stream>>>(offs, bsums, cursor);
    cheb_fill<<<eb, 256, 0, stream>>>(row, col, (const float*)deg, cursor, csr);

    int lb = N_NODES / NODES_PER_BLOCK;  // 3125 exactly
    cheb_layer<<<lb, 256, 0, stream>>>(emb, csr, offs, cnt, W1_0, W1_1, b1, h, 1);
    cheb_layer<<<lb, 256, 0, stream>>>(h, csr, offs, cnt, W2_0, W2_1, b2, out, 0);
}

// Round 2
// 507.993 us; speedup vs baseline: 1.1905x; 1.1905x over previous
//
#include <hip/hip_runtime.h>

#define N_NODES 100000
#define N_EDGES 1200000
#define NF 64

// ---------------- workspace layout (bytes) ----------------
#define OFF_DEG    0
#define OFF_CNT    400128
#define OFF_OFFS   800256
#define OFF_CURSOR 1200384
#define OFF_BSUMS  1600512
#define OFF_CSR    1602560
#define OFF_H      11202560

#define NB1 391   // ceil(100000/256)

__global__ __launch_bounds__(256) void cheb_hist(const int* __restrict__ row,
                                                 const int* __restrict__ col,
                                                 int* __restrict__ deg,
                                                 int* __restrict__ cnt) {
    int e = blockIdx.x * 256 + threadIdx.x;
    if (e < N_EDGES) {
        int s = row[e], d = col[e];
        if (s != d) {
            atomicAdd(&deg[s], 1);
            atomicAdd(&cnt[d], 1);
        }
    }
}

// fused: deg->dinv conversion + block-wise exclusive scan of cnt
__global__ __launch_bounds__(256) void cheb_scanA(int* __restrict__ deg_io,
                                                  const int* __restrict__ cnt,
                                                  int* __restrict__ offs,
                                                  int* __restrict__ bsums) {
    __shared__ int s[256];
    int t = threadIdx.x;
    int i = blockIdx.x * 256 + t;
    if (i < N_NODES) {
        int dg = deg_io[i];
        ((float*)deg_io)[i] = (dg > 0) ? rsqrtf((float)dg) : 0.0f;
    }
    int v = (i < N_NODES) ? cnt[i] : 0;
    s[t] = v;
    __syncthreads();
    for (int off = 1; off < 256; off <<= 1) {
        int add = (t >= off) ? s[t - off] : 0;
        __syncthreads();
        s[t] += add;
        __syncthreads();
    }
    if (i < N_NODES) offs[i] = s[t] - v;
    if (t == 255) bsums[blockIdx.x] = s[255];
}

__global__ __launch_bounds__(512) void cheb_scanB(int* __restrict__ bsums) {
    __shared__ int s[512];
    int t = threadIdx.x;
    int v = (t < NB1) ? bsums[t] : 0;
    s[t] = v;
    __syncthreads();
    for (int off = 1; off < 512; off <<= 1) {
        int add = (t >= off) ? s[t - off] : 0;
        __syncthreads();
        s[t] += add;
        __syncthreads();
    }
    if (t < NB1) bsums[t] = s[t] - v;
}

__global__ __launch_bounds__(256) void cheb_scanC(int* __restrict__ offs,
                                                  const int* __restrict__ bsums,
                                                  int* __restrict__ cursor) {
    int i = blockIdx.x * 256 + threadIdx.x;
    if (i < N_NODES) {
        int o = offs[i] + bsums[blockIdx.x];
        offs[i] = o;
        cursor[i] = o;
    }
}

__global__ __launch_bounds__(256) void cheb_fill(const int* __restrict__ row,
                                                 const int* __restrict__ col,
                                                 const float* __restrict__ dinv,
                                                 int* __restrict__ cursor,
                                                 int2* __restrict__ csr) {
    int e = blockIdx.x * 256 + threadIdx.x;
    if (e < N_EDGES) {
        int s = row[e], d = col[e];
        if (s != d) {
            float nrm = -dinv[s] * dinv[d];
            int idx = atomicAdd(&cursor[d], 1);
            csr[idx] = make_int2(s, __float_as_int(nrm));
        }
    }
}

// Fused: per-node aggregation (Tx1 gather, unroll-4) + GEMM (x@W0 + Tx1@W1 + b)
#define NODES_PER_WAVE 8
#define WAVES_PER_BLOCK 8
#define NODES_PER_BLOCK (NODES_PER_WAVE * WAVES_PER_BLOCK)   // 64
#define LB ((N_NODES + NODES_PER_BLOCK - 1) / NODES_PER_BLOCK)  // 1563

__global__ __launch_bounds__(512, 8) void cheb_layer(const float* __restrict__ x,
                                                     const int2* __restrict__ csr,
                                                     const int* __restrict__ offs,
                                                     const int* __restrict__ cnt,
                                                     const float* __restrict__ W0,
                                                     const float* __restrict__ W1,
                                                     const float* __restrict__ bias,
                                                     float* __restrict__ out,
                                                     int do_relu) {
    __shared__ float sW0[NF * NF];
    __shared__ float sW1[NF * NF];
    __shared__ float2 sXT[WAVES_PER_BLOCK][NF];

    int t = threadIdx.x;
    for (int i = t; i < NF * NF; i += 512) {
        sW0[i] = W0[i];
        sW1[i] = W1[i];
    }
    __syncthreads();

    int lane = t & 63;
    int wid = t >> 6;
    float bl = bias[lane];
    int base = blockIdx.x * NODES_PER_BLOCK + wid * NODES_PER_WAVE;

    for (int g = 0; g < NODES_PER_WAVE; ++g) {
        int node = base + g;
        bool valid = node < N_NODES;
        float xv = 0.0f;
        int start = 0, cn = 0;
        if (valid) {
            xv = x[node * NF + lane];
            start = __builtin_amdgcn_readfirstlane(offs[node]);
            cn = __builtin_amdgcn_readfirstlane(cnt[node]);
        }
        float a0 = 0.0f, a1 = 0.0f, a2 = 0.0f, a3 = 0.0f;
        int e = start, eend = start + cn;
        for (; e + 4 <= eend; e += 4) {
            int2 p0 = csr[e + 0];
            int2 p1 = csr[e + 1];
            int2 p2 = csr[e + 2];
            int2 p3 = csr[e + 3];
            a0 = fmaf(__int_as_float(p0.y), x[p0.x * NF + lane], a0);
            a1 = fmaf(__int_as_float(p1.y), x[p1.x * NF + lane], a1);
            a2 = fmaf(__int_as_float(p2.y), x[p2.x * NF + lane], a2);
            a3 = fmaf(__int_as_float(p3.y), x[p3.x * NF + lane], a3);
        }
        for (; e < eend; ++e) {
            int2 p = csr[e];
            a0 = fmaf(__int_as_float(p.y), x[p.x * NF + lane], a0);
        }
        float acc = (a0 + a1) + (a2 + a3);

        sXT[wid][lane] = make_float2(xv, acc);
        __builtin_amdgcn_wave_barrier();

        float o = bl;
#pragma unroll
        for (int l = 0; l < NF; ++l) {
            float2 p = sXT[wid][l];
            o = fmaf(p.x, sW0[l * NF + lane], o);
            o = fmaf(p.y, sW1[l * NF + lane], o);
        }
        if (do_relu) o = fmaxf(o, 0.0f);
        if (valid) out[node * NF + lane] = o;
        __builtin_amdgcn_wave_barrier();
    }
}

extern "C" void kernel_launch(void* const* d_in, const int* in_sizes, int n_in,
                              void* d_out, int out_size, void* d_ws, size_t ws_size,
                              hipStream_t stream) {
    const int* ei = (const int*)d_in[0];
    const int* row = ei;
    const int* col = ei + N_EDGES;
    const float* emb = (const float*)d_in[1];
    const float* W1_0 = (const float*)d_in[2];
    const float* W1_1 = (const float*)d_in[3];
    const float* b1 = (const float*)d_in[4];
    const float* W2_0 = (const float*)d_in[5];
    const float* W2_1 = (const float*)d_in[6];
    const float* b2 = (const float*)d_in[7];
    float* out = (float*)d_out;

    char* ws = (char*)d_ws;
    int* deg = (int*)(ws + OFF_DEG);
    int* cnt = (int*)(ws + OFF_CNT);
    int* offs = (int*)(ws + OFF_OFFS);
    int* cursor = (int*)(ws + OFF_CURSOR);
    int* bsums = (int*)(ws + OFF_BSUMS);
    int2* csr = (int2*)(ws + OFF_CSR);
    float* h = (float*)(ws + OFF_H);

    hipMemsetAsync(deg, 0, N_NODES * sizeof(int), stream);
    hipMemsetAsync(cnt, 0, N_NODES * sizeof(int), stream);

    int eb = (N_EDGES + 255) / 256;
    cheb_hist<<<eb, 256, 0, stream>>>(row, col, deg, cnt);
    cheb_scanA<<<NB1, 256, 0, stream>>>(deg, cnt, offs, bsums);
    cheb_scanB<<<1, 512, 0, stream>>>(bsums);
    cheb_scanC<<<NB1, 256, 0, stream>>>(offs, bsums, cursor);
    cheb_fill<<<eb, 256, 0, stream>>>(row, col, (const float*)deg, cursor, csr);

    cheb_layer<<<LB, 512, 0, stream>>>(emb, csr, offs, cnt, W1_0, W1_1, b1, h, 1);
    cheb_layer<<<LB, 512, 0, stream>>>(h, csr, offs, cnt, W2_0, W2_1, b2, out, 0);
}

// Round 3
// 395.357 us; speedup vs baseline: 1.5297x; 1.2849x over previous
//
#include <hip/hip_runtime.h>

#define N_NODES 100000
#define N_EDGES 1200000
#define NF 64

// ---------------- workspace layout (bytes) ----------------
#define OFF_DEG    0
#define OFF_CNT    400128
#define OFF_CURSOR 800256
#define OFF_BSUMS  1200384
#define OFF_CSR    1202560
#define OFF_H      10802560

#define NB1 391   // ceil(100000/256)

__global__ __launch_bounds__(256) void cheb_hist(const int* __restrict__ row,
                                                 const int* __restrict__ col,
                                                 int* __restrict__ deg,
                                                 int* __restrict__ cnt) {
    int e = blockIdx.x * 256 + threadIdx.x;
    if (e < N_EDGES) {
        int s = row[e], d = col[e];
        if (s != d) {
            atomicAdd(&deg[s], 1);
            atomicAdd(&cnt[d], 1);
        }
    }
}

// fused: deg->dinv conversion + block-wise exclusive scan of cnt -> cursor
__global__ __launch_bounds__(256) void cheb_scanA(int* __restrict__ deg_io,
                                                  const int* __restrict__ cnt,
                                                  int* __restrict__ cursor,
                                                  int* __restrict__ bsums) {
    __shared__ int s[256];
    int t = threadIdx.x;
    int i = blockIdx.x * 256 + t;
    if (i < N_NODES) {
        int dg = deg_io[i];
        ((float*)deg_io)[i] = (dg > 0) ? rsqrtf((float)dg) : 0.0f;
    }
    int v = (i < N_NODES) ? cnt[i] : 0;
    s[t] = v;
    __syncthreads();
    for (int off = 1; off < 256; off <<= 1) {
        int add = (t >= off) ? s[t - off] : 0;
        __syncthreads();
        s[t] += add;
        __syncthreads();
    }
    if (i < N_NODES) cursor[i] = s[t] - v;
    if (t == 255) bsums[blockIdx.x] = s[255];
}

__global__ __launch_bounds__(512) void cheb_scanB(int* __restrict__ bsums) {
    __shared__ int s[512];
    int t = threadIdx.x;
    int v = (t < NB1) ? bsums[t] : 0;
    s[t] = v;
    __syncthreads();
    for (int off = 1; off < 512; off <<= 1) {
        int add = (t >= off) ? s[t - off] : 0;
        __syncthreads();
        s[t] += add;
        __syncthreads();
    }
    if (t < NB1) bsums[t] = s[t] - v;
}

__global__ __launch_bounds__(256) void cheb_scanC(int* __restrict__ cursor,
                                                  const int* __restrict__ bsums) {
    int i = blockIdx.x * 256 + threadIdx.x;
    if (i < N_NODES) cursor[i] += bsums[blockIdx.x];
}

// counting-sort edges by dst; afterwards cursor[d] == bucket END (start = end - cnt)
__global__ __launch_bounds__(256) void cheb_fill(const int* __restrict__ row,
                                                 const int* __restrict__ col,
                                                 const float* __restrict__ dinv,
                                                 int* __restrict__ cursor,
                                                 int2* __restrict__ csr) {
    int e = blockIdx.x * 256 + threadIdx.x;
    if (e < N_EDGES) {
        int s = row[e], d = col[e];
        if (s != d) {
            float nrm = -dinv[s] * dinv[d];
            int idx = atomicAdd(&cursor[d], 1);
            csr[idx] = make_int2(s, __float_as_int(nrm));
        }
    }
}

// Fused layer: per-wave aggregation of 4 nodes (unroll-8 gather) then a
// 4-node batched GEMM that amortizes W LDS reads 4x and reads sXT as b128.
#define NODES_PER_WAVE 8
#define WAVES_PER_BLOCK 8
#define NODES_PER_BLOCK (NODES_PER_WAVE * WAVES_PER_BLOCK)       // 64
#define LB ((N_NODES + NODES_PER_BLOCK - 1) / NODES_PER_BLOCK)   // 1563

__global__ __launch_bounds__(512, 6) void cheb_layer(const float* __restrict__ x,
                                                     const int2* __restrict__ csr,
                                                     const int* __restrict__ endp,
                                                     const int* __restrict__ cnt,
                                                     const float* __restrict__ W0,
                                                     const float* __restrict__ W1,
                                                     const float* __restrict__ bias,
                                                     float* __restrict__ out,
                                                     int do_relu) {
    __shared__ float sW0[NF * NF];               // 16 KB
    __shared__ float sW1[NF * NF];               // 16 KB
    __shared__ float2 sXT[WAVES_PER_BLOCK][4][NF]; // 16 KB, [wid][g][l]

    int t = threadIdx.x;
    for (int i = t; i < NF * NF; i += 512) {
        sW0[i] = W0[i];
        sW1[i] = W1[i];
    }
    __syncthreads();

    int lane = t & 63;
    int wid = t >> 6;
    float bl = bias[lane];
    int base = blockIdx.x * NODES_PER_BLOCK + wid * NODES_PER_WAVE;

    // lanes 0..7 hold the wave's 8 nodes' (end, cnt); distributed via readlane
    int nend = 0, ncnt = 0;
    if (lane < NODES_PER_WAVE && base + lane < N_NODES) {
        nend = endp[base + lane];
        ncnt = cnt[base + lane];
    }

    for (int half = 0; half < 2; ++half) {
        int gbase = half * 4;

        // ---- aggregate 4 nodes ----
#pragma unroll
        for (int g = 0; g < 4; ++g) {
            int node = base + gbase + g;
            int cn   = __builtin_amdgcn_readlane(ncnt, gbase + g);
            int eend = __builtin_amdgcn_readlane(nend, gbase + g);
            int e = eend - cn;
            float xv = (node < N_NODES) ? x[node * NF + lane] : 0.0f;
            float a0 = 0, a1 = 0, a2 = 0, a3 = 0, a4 = 0, a5 = 0, a6 = 0, a7 = 0;
            for (; e + 8 <= eend; e += 8) {
                int2 p0 = csr[e + 0], p1 = csr[e + 1], p2 = csr[e + 2], p3 = csr[e + 3];
                int2 p4 = csr[e + 4], p5 = csr[e + 5], p6 = csr[e + 6], p7 = csr[e + 7];
                a0 = fmaf(__int_as_float(p0.y), x[p0.x * NF + lane], a0);
                a1 = fmaf(__int_as_float(p1.y), x[p1.x * NF + lane], a1);
                a2 = fmaf(__int_as_float(p2.y), x[p2.x * NF + lane], a2);
                a3 = fmaf(__int_as_float(p3.y), x[p3.x * NF + lane], a3);
                a4 = fmaf(__int_as_float(p4.y), x[p4.x * NF + lane], a4);
                a5 = fmaf(__int_as_float(p5.y), x[p5.x * NF + lane], a5);
                a6 = fmaf(__int_as_float(p6.y), x[p6.x * NF + lane], a6);
                a7 = fmaf(__int_as_float(p7.y), x[p7.x * NF + lane], a7);
            }
            if (e + 4 <= eend) {
                int2 p0 = csr[e + 0], p1 = csr[e + 1], p2 = csr[e + 2], p3 = csr[e + 3];
                a0 = fmaf(__int_as_float(p0.y), x[p0.x * NF + lane], a0);
                a1 = fmaf(__int_as_float(p1.y), x[p1.x * NF + lane], a1);
                a2 = fmaf(__int_as_float(p2.y), x[p2.x * NF + lane], a2);
                a3 = fmaf(__int_as_float(p3.y), x[p3.x * NF + lane], a3);
                e += 4;
            }
            if (e + 2 <= eend) {
                int2 p0 = csr[e + 0], p1 = csr[e + 1];
                a0 = fmaf(__int_as_float(p0.y), x[p0.x * NF + lane], a0);
                a1 = fmaf(__int_as_float(p1.y), x[p1.x * NF + lane], a1);
                e += 2;
            }
            if (e < eend) {
                int2 p0 = csr[e];
                a0 = fmaf(__int_as_float(p0.y), x[p0.x * NF + lane], a0);
            }
            float acc = ((a0 + a1) + (a2 + a3)) + ((a4 + a5) + (a6 + a7));
            sXT[wid][g][lane] = make_float2(xv, acc);
        }
        __builtin_amdgcn_wave_barrier();

        // ---- batched GEMM for the 4 nodes ----
        float o0 = bl, o1 = bl, o2 = bl, o3 = bl;
#pragma unroll 8
        for (int l = 0; l < NF; l += 2) {
            float w0a = sW0[l * NF + lane];
            float w1a = sW1[l * NF + lane];
            float w0b = sW0[(l + 1) * NF + lane];
            float w1b = sW1[(l + 1) * NF + lane];
            float4 q0 = *(const float4*)&sXT[wid][0][l];  // (x_l, t_l, x_l+1, t_l+1)
            float4 q1 = *(const float4*)&sXT[wid][1][l];
            float4 q2 = *(const float4*)&sXT[wid][2][l];
            float4 q3 = *(const float4*)&sXT[wid][3][l];
            o0 = fmaf(q0.x, w0a, fmaf(q0.y, w1a, fmaf(q0.z, w0b, fmaf(q0.w, w1b, o0))));
            o1 = fmaf(q1.x, w0a, fmaf(q1.y, w1a, fmaf(q1.z, w0b, fmaf(q1.w, w1b, o1))));
            o2 = fmaf(q2.x, w0a, fmaf(q2.y, w1a, fmaf(q2.z, w0b, fmaf(q2.w, w1b, o2))));
            o3 = fmaf(q3.x, w0a, fmaf(q3.y, w1a, fmaf(q3.z, w0b, fmaf(q3.w, w1b, o3))));
        }
        if (do_relu) {
            o0 = fmaxf(o0, 0.0f); o1 = fmaxf(o1, 0.0f);
            o2 = fmaxf(o2, 0.0f); o3 = fmaxf(o3, 0.0f);
        }
        int n0 = base + gbase;
        if (n0 + 0 < N_NODES) out[(n0 + 0) * NF + lane] = o0;
        if (n0 + 1 < N_NODES) out[(n0 + 1) * NF + lane] = o1;
        if (n0 + 2 < N_NODES) out[(n0 + 2) * NF + lane] = o2;
        if (n0 + 3 < N_NODES) out[(n0 + 3) * NF + lane] = o3;
        __builtin_amdgcn_wave_barrier();
    }
}

extern "C" void kernel_launch(void* const* d_in, const int* in_sizes, int n_in,
                              void* d_out, int out_size, void* d_ws, size_t ws_size,
                              hipStream_t stream) {
    const int* ei = (const int*)d_in[0];
    const int* row = ei;
    const int* col = ei + N_EDGES;
    const float* emb = (const float*)d_in[1];
    const float* W1_0 = (const float*)d_in[2];
    const float* W1_1 = (const float*)d_in[3];
    const float* b1 = (const float*)d_in[4];
    const float* W2_0 = (const float*)d_in[5];
    const float* W2_1 = (const float*)d_in[6];
    const float* b2 = (const float*)d_in[7];
    float* out = (float*)d_out;

    char* ws = (char*)d_ws;
    int* deg = (int*)(ws + OFF_DEG);
    int* cnt = (int*)(ws + OFF_CNT);
    int* cursor = (int*)(ws + OFF_CURSOR);
    int* bsums = (int*)(ws + OFF_BSUMS);
    int2* csr = (int2*)(ws + OFF_CSR);
    float* h = (float*)(ws + OFF_H);

    hipMemsetAsync(deg, 0, N_NODES * sizeof(int), stream);
    hipMemsetAsync(cnt, 0, N_NODES * sizeof(int), stream);

    int eb = (N_EDGES + 255) / 256;
    cheb_hist<<<eb, 256, 0, stream>>>(row, col, deg, cnt);
    cheb_scanA<<<NB1, 256, 0, stream>>>(deg, cnt, cursor, bsums);
    cheb_scanB<<<1, 512, 0, stream>>>(bsums);
    cheb_scanC<<<NB1, 256, 0, stream>>>(cursor, bsums);
    cheb_fill<<<eb, 256, 0, stream>>>(row, col, (const float*)deg, cursor, csr);

    cheb_layer<<<LB, 512, 0, stream>>>(emb, csr, cursor, cnt, W1_0, W1_1, b1, h, 1);
    cheb_layer<<<LB, 512, 0, stream>>>(h, csr, cursor, cnt, W2_0, W2_1, b2, out, 0);
}

// Round 4
// 299.993 us; speedup vs baseline: 2.0160x; 1.3179x over previous
//
#include <hip/hip_runtime.h>

#define N_NODES 100000
#define N_EDGES 1200000
#define NF 64

// binning
#define NBINS 196            // ceil(100000 / 512), bin = node >> 9
#define EPB 5120             // edges per block in binA/binC (256 thr x 20)
#define NBLK 235             // ceil(1200000 / 5120)
#define CLEN (2 * NBINS * NBLK)   // 92120 (src hists then dst hists)
#define SCAN_BLOCKS 360      // ceil(CLEN / 256)

// ---------------- workspace layout (bytes), peak 36.4 MB ----------------
#define OFF_DINV    0              // float[100000]
#define OFF_CNT     400128         // int[100000]
#define OFF_ENDP    800256         // int[100000]
#define OFF_BSUMS   1200384        // int[360] (pad)
#define OFF_CSR     1203200        // int2[1200000] = 9.6 MB
#define OFF_SCRATCH 10803200       // preprocessing scratch, later h
//   sbinned : SCRATCH + 0        int[1200000]  (4.8 MB)
//   dbinned : SCRATCH + 4800000  int2[1200000] (9.6 MB)
//   counts  : SCRATCH + 14400000 int[CLEN]
//   offs    : SCRATCH + 14800000 int[CLEN]
// h (layer-1 out, float[100000*64] = 25.6 MB) overlays SCRATCH after
// preprocessing is complete.

// Phase A: per-block LDS histograms by src-bin and dst-bin (no global atomics)
__global__ __launch_bounds__(256) void binA(const int* __restrict__ row,
                                            const int* __restrict__ col,
                                            int* __restrict__ counts) {
    __shared__ int sh[NBINS], dh[NBINS];
    int t = threadIdx.x;
    for (int i = t; i < NBINS; i += 256) { sh[i] = 0; dh[i] = 0; }
    __syncthreads();
    int base = blockIdx.x * EPB;
    for (int k = 0; k < 20; ++k) {
        int e = base + k * 256 + t;
        if (e < N_EDGES) {
            int s = row[e], d = col[e];
            if (s != d) {
                atomicAdd(&sh[s >> 9], 1);
                atomicAdd(&dh[d >> 9], 1);
            }
        }
    }
    __syncthreads();
    for (int i = t; i < NBINS; i += 256) {
        counts[i * NBLK + blockIdx.x] = sh[i];
        counts[(NBINS + i) * NBLK + blockIdx.x] = dh[i];
    }
}

__global__ __launch_bounds__(256) void scanA(const int* __restrict__ in,
                                             int* __restrict__ out,
                                             int* __restrict__ bsums) {
    __shared__ int s[256];
    int t = threadIdx.x, i = blockIdx.x * 256 + t;
    int v = (i < CLEN) ? in[i] : 0;
    s[t] = v;
    __syncthreads();
    for (int off = 1; off < 256; off <<= 1) {
        int a = (t >= off) ? s[t - off] : 0;
        __syncthreads();
        s[t] += a;
        __syncthreads();
    }
    if (i < CLEN) out[i] = s[t] - v;
    if (t == 255) bsums[blockIdx.x] = s[255];
}

__global__ __launch_bounds__(512) void scanB(int* __restrict__ bsums) {
    __shared__ int s[512];
    int t = threadIdx.x;
    int v = (t < SCAN_BLOCKS) ? bsums[t] : 0;
    s[t] = v;
    __syncthreads();
    for (int off = 1; off < 512; off <<= 1) {
        int a = (t >= off) ? s[t - off] : 0;
        __syncthreads();
        s[t] += a;
        __syncthreads();
    }
    if (t < SCAN_BLOCKS) bsums[t] = s[t] - v;
}

__global__ __launch_bounds__(256) void scanC(int* __restrict__ out,
                                             const int* __restrict__ bsums) {
    int i = blockIdx.x * 256 + threadIdx.x;
    if (i < CLEN) out[i] += bsums[blockIdx.x];
}

// Phase C: place edges into binned arrays via LDS cursors (no global atomics)
__global__ __launch_bounds__(256) void binC(const int* __restrict__ row,
                                            const int* __restrict__ col,
                                            const int* __restrict__ offs,
                                            int* __restrict__ sbinned,
                                            int2* __restrict__ dbinned) {
    __shared__ int cur[2 * NBINS];
    int t = threadIdx.x;
    for (int i = t; i < 2 * NBINS; i += 256) cur[i] = offs[i * NBLK + blockIdx.x];
    __syncthreads();
    int E1 = offs[NBINS * NBLK];  // total non-self edges (sum of all src counts)
    int base = blockIdx.x * EPB;
    for (int k = 0; k < 20; ++k) {
        int e = base + k * 256 + t;
        if (e < N_EDGES) {
            int s = row[e], d = col[e];
            if (s != d) {
                int ss = atomicAdd(&cur[s >> 9], 1);
                sbinned[ss] = s;
                int ds = atomicAdd(&cur[NBINS + (d >> 9)], 1);
                dbinned[ds - E1] = make_int2(s, d);
            }
        }
    }
}

// Phase D1: per src-bin LDS per-node histogram -> dinv (coalesced write)
__global__ __launch_bounds__(256) void binD1(const int* __restrict__ sbinned,
                                             const int* __restrict__ offs,
                                             float* __restrict__ dinv) {
    __shared__ int hist[512];
    int t = threadIdx.x;
    hist[t] = 0; hist[t + 256] = 0;
    __syncthreads();
    int b = blockIdx.x;
    int E1 = offs[NBINS * NBLK];
    int start = offs[b * NBLK];
    int end = (b == NBINS - 1) ? E1 : offs[(b + 1) * NBLK];
    for (int i = start + t; i < end; i += 256)
        atomicAdd(&hist[sbinned[i] - (b << 9)], 1);
    __syncthreads();
    int n0 = (b << 9) + t, n1 = n0 + 256;
    if (n0 < N_NODES) dinv[n0] = hist[t] ? rsqrtf((float)hist[t]) : 0.0f;
    if (n1 < N_NODES) dinv[n1] = hist[t + 256] ? rsqrtf((float)hist[t + 256]) : 0.0f;
}

// Phase D2: per dst-bin histogram + LDS scan -> cnt/endp, then CSR placement
__global__ __launch_bounds__(256) void binD2(const int2* __restrict__ dbinned,
                                             const int* __restrict__ offs,
                                             const float* __restrict__ dinv,
                                             int* __restrict__ cnt,
                                             int* __restrict__ endp,
                                             int2* __restrict__ csr) {
    __shared__ int hist[512];
    __shared__ int lcur[512];
    int t = threadIdx.x;
    hist[t] = 0; hist[t + 256] = 0;
    __syncthreads();
    int b = blockIdx.x;
    int E1 = offs[NBINS * NBLK];
    int start = offs[(NBINS + b) * NBLK] - E1;
    int end = (b == NBINS - 1) ? E1 : offs[(NBINS + b + 1) * NBLK] - E1;
    for (int i = start + t; i < end; i += 256)
        atomicAdd(&hist[dbinned[i].y - (b << 9)], 1);
    __syncthreads();
    int o0 = hist[t], o1 = hist[t + 256];
    // inclusive Hillis-Steele scan over 512 elements with 256 threads
    for (int off = 1; off < 512; off <<= 1) {
        int v0 = (t >= off) ? hist[t - off] : 0;
        int v1 = (t + 256 >= off) ? hist[t + 256 - off] : 0;
        __syncthreads();
        hist[t] += v0; hist[t + 256] += v1;
        __syncthreads();
    }
    int e0 = hist[t] - o0, e1 = hist[t + 256] - o1;  // exclusive
    lcur[t] = start + e0;
    lcur[t + 256] = start + e1;
    int n0 = (b << 9) + t, n1 = n0 + 256;
    if (n0 < N_NODES) { cnt[n0] = o0; endp[n0] = start + e0 + o0; }
    if (n1 < N_NODES) { cnt[n1] = o1; endp[n1] = start + e1 + o1; }
    __syncthreads();
    for (int i = start + t; i < end; i += 256) {
        int2 r = dbinned[i];
        int slot = atomicAdd(&lcur[r.y - (b << 9)], 1);
        float nrm = -dinv[r.x] * dinv[r.y];
        csr[slot] = make_int2(r.x, __float_as_int(nrm));
    }
}

// Fused layer (unchanged from round 3)
#define NODES_PER_WAVE 8
#define WAVES_PER_BLOCK 8
#define NODES_PER_BLOCK (NODES_PER_WAVE * WAVES_PER_BLOCK)       // 64
#define LB ((N_NODES + NODES_PER_BLOCK - 1) / NODES_PER_BLOCK)   // 1563

__global__ __launch_bounds__(512, 6) void cheb_layer(const float* __restrict__ x,
                                                     const int2* __restrict__ csr,
                                                     const int* __restrict__ endp,
                                                     const int* __restrict__ cnt,
                                                     const float* __restrict__ W0,
                                                     const float* __restrict__ W1,
                                                     const float* __restrict__ bias,
                                                     float* __restrict__ out,
                                                     int do_relu) {
    __shared__ float sW0[NF * NF];
    __shared__ float sW1[NF * NF];
    __shared__ float2 sXT[WAVES_PER_BLOCK][4][NF];

    int t = threadIdx.x;
    for (int i = t; i < NF * NF; i += 512) {
        sW0[i] = W0[i];
        sW1[i] = W1[i];
    }
    __syncthreads();

    int lane = t & 63;
    int wid = t >> 6;
    float bl = bias[lane];
    int base = blockIdx.x * NODES_PER_BLOCK + wid * NODES_PER_WAVE;

    int nend = 0, ncnt = 0;
    if (lane < NODES_PER_WAVE && base + lane < N_NODES) {
        nend = endp[base + lane];
        ncnt = cnt[base + lane];
    }

    for (int half = 0; half < 2; ++half) {
        int gbase = half * 4;
#pragma unroll
        for (int g = 0; g < 4; ++g) {
            int node = base + gbase + g;
            int cn   = __builtin_amdgcn_readlane(ncnt, gbase + g);
            int eend = __builtin_amdgcn_readlane(nend, gbase + g);
            int e = eend - cn;
            float xv = (node < N_NODES) ? x[node * NF + lane] : 0.0f;
            float a0 = 0, a1 = 0, a2 = 0, a3 = 0, a4 = 0, a5 = 0, a6 = 0, a7 = 0;
            for (; e + 8 <= eend; e += 8) {
                int2 p0 = csr[e + 0], p1 = csr[e + 1], p2 = csr[e + 2], p3 = csr[e + 3];
                int2 p4 = csr[e + 4], p5 = csr[e + 5], p6 = csr[e + 6], p7 = csr[e + 7];
                a0 = fmaf(__int_as_float(p0.y), x[p0.x * NF + lane], a0);
                a1 = fmaf(__int_as_float(p1.y), x[p1.x * NF + lane], a1);
                a2 = fmaf(__int_as_float(p2.y), x[p2.x * NF + lane], a2);
                a3 = fmaf(__int_as_float(p3.y), x[p3.x * NF + lane], a3);
                a4 = fmaf(__int_as_float(p4.y), x[p4.x * NF + lane], a4);
                a5 = fmaf(__int_as_float(p5.y), x[p5.x * NF + lane], a5);
                a6 = fmaf(__int_as_float(p6.y), x[p6.x * NF + lane], a6);
                a7 = fmaf(__int_as_float(p7.y), x[p7.x * NF + lane], a7);
            }
            if (e + 4 <= eend) {
                int2 p0 = csr[e + 0], p1 = csr[e + 1], p2 = csr[e + 2], p3 = csr[e + 3];
                a0 = fmaf(__int_as_float(p0.y), x[p0.x * NF + lane], a0);
                a1 = fmaf(__int_as_float(p1.y), x[p1.x * NF + lane], a1);
                a2 = fmaf(__int_as_float(p2.y), x[p2.x * NF + lane], a2);
                a3 = fmaf(__int_as_float(p3.y), x[p3.x * NF + lane], a3);
                e += 4;
            }
            if (e + 2 <= eend) {
                int2 p0 = csr[e + 0], p1 = csr[e + 1];
                a0 = fmaf(__int_as_float(p0.y), x[p0.x * NF + lane], a0);
                a1 = fmaf(__int_as_float(p1.y), x[p1.x * NF + lane], a1);
                e += 2;
            }
            if (e < eend) {
                int2 p0 = csr[e];
                a0 = fmaf(__int_as_float(p0.y), x[p0.x * NF + lane], a0);
            }
            float acc = ((a0 + a1) + (a2 + a3)) + ((a4 + a5) + (a6 + a7));
            sXT[wid][g][lane] = make_float2(xv, acc);
        }
        __builtin_amdgcn_wave_barrier();

        float o0 = bl, o1 = bl, o2 = bl, o3 = bl;
#pragma unroll 8
        for (int l = 0; l < NF; l += 2) {
            float w0a = sW0[l * NF + lane];
            float w1a = sW1[l * NF + lane];
            float w0b = sW0[(l + 1) * NF + lane];
            float w1b = sW1[(l + 1) * NF + lane];
            float4 q0 = *(const float4*)&sXT[wid][0][l];
            float4 q1 = *(const float4*)&sXT[wid][1][l];
            float4 q2 = *(const float4*)&sXT[wid][2][l];
            float4 q3 = *(const float4*)&sXT[wid][3][l];
            o0 = fmaf(q0.x, w0a, fmaf(q0.y, w1a, fmaf(q0.z, w0b, fmaf(q0.w, w1b, o0))));
            o1 = fmaf(q1.x, w0a, fmaf(q1.y, w1a, fmaf(q1.z, w0b, fmaf(q1.w, w1b, o1))));
            o2 = fmaf(q2.x, w0a, fmaf(q2.y, w1a, fmaf(q2.z, w0b, fmaf(q2.w, w1b, o2))));
            o3 = fmaf(q3.x, w0a, fmaf(q3.y, w1a, fmaf(q3.z, w0b, fmaf(q3.w, w1b, o3))));
        }
        if (do_relu) {
            o0 = fmaxf(o0, 0.0f); o1 = fmaxf(o1, 0.0f);
            o2 = fmaxf(o2, 0.0f); o3 = fmaxf(o3, 0.0f);
        }
        int n0 = base + gbase;
        if (n0 + 0 < N_NODES) out[(n0 + 0) * NF + lane] = o0;
        if (n0 + 1 < N_NODES) out[(n0 + 1) * NF + lane] = o1;
        if (n0 + 2 < N_NODES) out[(n0 + 2) * NF + lane] = o2;
        if (n0 + 3 < N_NODES) out[(n0 + 3) * NF + lane] = o3;
        __builtin_amdgcn_wave_barrier();
    }
}

extern "C" void kernel_launch(void* const* d_in, const int* in_sizes, int n_in,
                              void* d_out, int out_size, void* d_ws, size_t ws_size,
                              hipStream_t stream) {
    const int* ei = (const int*)d_in[0];
    const int* row = ei;
    const int* col = ei + N_EDGES;
    const float* emb = (const float*)d_in[1];
    const float* W1_0 = (const float*)d_in[2];
    const float* W1_1 = (const float*)d_in[3];
    const float* b1 = (const float*)d_in[4];
    const float* W2_0 = (const float*)d_in[5];
    const float* W2_1 = (const float*)d_in[6];
    const float* b2 = (const float*)d_in[7];
    float* out = (float*)d_out;

    char* ws = (char*)d_ws;
    float* dinv = (float*)(ws + OFF_DINV);
    int* cnt = (int*)(ws + OFF_CNT);
    int* endp = (int*)(ws + OFF_ENDP);
    int* bsums = (int*)(ws + OFF_BSUMS);
    int2* csr = (int2*)(ws + OFF_CSR);
    char* scratch = ws + OFF_SCRATCH;
    int* sbinned = (int*)(scratch);
    int2* dbinned = (int2*)(scratch + 4800000);
    int* counts = (int*)(scratch + 14400000);
    int* offs = (int*)(scratch + 14800000);
    float* h = (float*)(ws + OFF_SCRATCH);   // overlays scratch after preprocessing

    binA<<<NBLK, 256, 0, stream>>>(row, col, counts);
    scanA<<<SCAN_BLOCKS, 256, 0, stream>>>(counts, offs, bsums);
    scanB<<<1, 512, 0, stream>>>(bsums);
    scanC<<<SCAN_BLOCKS, 256, 0, stream>>>(offs, bsums);
    binC<<<NBLK, 256, 0, stream>>>(row, col, offs, sbinned, dbinned);
    binD1<<<NBINS, 256, 0, stream>>>(sbinned, offs, dinv);
    binD2<<<NBINS, 256, 0, stream>>>(dbinned, offs, dinv, cnt, endp, csr);

    cheb_layer<<<LB, 512, 0, stream>>>(emb, csr, endp, cnt, W1_0, W1_1, b1, h, 1);
    cheb_layer<<<LB, 512, 0, stream>>>(h, csr, endp, cnt, W2_0, W2_1, b2, out, 0);
}

// Round 5
// 279.398 us; speedup vs baseline: 2.1646x; 1.0737x over previous
//
#include <hip/hip_runtime.h>

#define N_NODES 100000
#define N_EDGES 1200000
#define NF 64

typedef __attribute__((ext_vector_type(8))) short short8;
typedef __attribute__((ext_vector_type(4))) float float4v;

__device__ __forceinline__ ushort f2bf(float f) {
    unsigned u = __float_as_uint(f);
    return (ushort)((u + 0x7FFF + ((u >> 16) & 1)) >> 16);  // RNE
}
__device__ __forceinline__ float bf2f(ushort b) {
    return __uint_as_float(((unsigned)b) << 16);
}

// binning
#define NBINS 196
#define EPB 5120
#define NBLK 235
#define CLEN (2 * NBINS * NBLK)
#define SCAN_BLOCKS 360

// ---------------- workspace layout (bytes), peak 36.4 MB ----------------
#define OFF_DINV    0
#define OFF_CNT     400128
#define OFF_ENDP    800256
#define OFF_BSUMS   1200384
#define OFF_CSR     1203200
#define OFF_SCRATCH 10803200
// preprocessing overlay: sbinned/dbinned/counts/offs (dead after binD2)
// then: emb_bf @ SCRATCH+0 (12.8MB), h_bf @ SCRATCH+12800000 (12.8MB)

__global__ __launch_bounds__(256) void binA(const int* __restrict__ row,
                                            const int* __restrict__ col,
                                            int* __restrict__ counts) {
    __shared__ int sh[NBINS], dh[NBINS];
    int t = threadIdx.x;
    for (int i = t; i < NBINS; i += 256) { sh[i] = 0; dh[i] = 0; }
    __syncthreads();
    int base = blockIdx.x * EPB;
    for (int k = 0; k < 20; ++k) {
        int e = base + k * 256 + t;
        if (e < N_EDGES) {
            int s = row[e], d = col[e];
            if (s != d) {
                atomicAdd(&sh[s >> 9], 1);
                atomicAdd(&dh[d >> 9], 1);
            }
        }
    }
    __syncthreads();
    for (int i = t; i < NBINS; i += 256) {
        counts[i * NBLK + blockIdx.x] = sh[i];
        counts[(NBINS + i) * NBLK + blockIdx.x] = dh[i];
    }
}

__global__ __launch_bounds__(256) void scanA(const int* __restrict__ in,
                                             int* __restrict__ out,
                                             int* __restrict__ bsums) {
    __shared__ int s[256];
    int t = threadIdx.x, i = blockIdx.x * 256 + t;
    int v = (i < CLEN) ? in[i] : 0;
    s[t] = v;
    __syncthreads();
    for (int off = 1; off < 256; off <<= 1) {
        int a = (t >= off) ? s[t - off] : 0;
        __syncthreads();
        s[t] += a;
        __syncthreads();
    }
    if (i < CLEN) out[i] = s[t] - v;
    if (t == 255) bsums[blockIdx.x] = s[255];
}

__global__ __launch_bounds__(512) void scanB(int* __restrict__ bsums) {
    __shared__ int s[512];
    int t = threadIdx.x;
    int v = (t < SCAN_BLOCKS) ? bsums[t] : 0;
    s[t] = v;
    __syncthreads();
    for (int off = 1; off < 512; off <<= 1) {
        int a = (t >= off) ? s[t - off] : 0;
        __syncthreads();
        s[t] += a;
        __syncthreads();
    }
    if (t < SCAN_BLOCKS) bsums[t] = s[t] - v;
}

__global__ __launch_bounds__(256) void scanC(int* __restrict__ out,
                                             const int* __restrict__ bsums) {
    int i = blockIdx.x * 256 + threadIdx.x;
    if (i < CLEN) out[i] += bsums[blockIdx.x];
}

__global__ __launch_bounds__(256) void binC(const int* __restrict__ row,
                                            const int* __restrict__ col,
                                            const int* __restrict__ offs,
                                            int* __restrict__ sbinned,
                                            int2* __restrict__ dbinned) {
    __shared__ int cur[2 * NBINS];
    int t = threadIdx.x;
    for (int i = t; i < 2 * NBINS; i += 256) cur[i] = offs[i * NBLK + blockIdx.x];
    __syncthreads();
    int E1 = offs[NBINS * NBLK];
    int base = blockIdx.x * EPB;
    for (int k = 0; k < 20; ++k) {
        int e = base + k * 256 + t;
        if (e < N_EDGES) {
            int s = row[e], d = col[e];
            if (s != d) {
                int ss = atomicAdd(&cur[s >> 9], 1);
                sbinned[ss] = s;
                int ds = atomicAdd(&cur[NBINS + (d >> 9)], 1);
                dbinned[ds - E1] = make_int2(s, d);
            }
        }
    }
}

__global__ __launch_bounds__(256) void binD1(const int* __restrict__ sbinned,
                                             const int* __restrict__ offs,
                                             float* __restrict__ dinv) {
    __shared__ int hist[512];
    int t = threadIdx.x;
    hist[t] = 0; hist[t + 256] = 0;
    __syncthreads();
    int b = blockIdx.x;
    int E1 = offs[NBINS * NBLK];
    int start = offs[b * NBLK];
    int end = (b == NBINS - 1) ? E1 : offs[(b + 1) * NBLK];
    for (int i = start + t; i < end; i += 256)
        atomicAdd(&hist[sbinned[i] - (b << 9)], 1);
    __syncthreads();
    int n0 = (b << 9) + t, n1 = n0 + 256;
    if (n0 < N_NODES) dinv[n0] = hist[t] ? rsqrtf((float)hist[t]) : 0.0f;
    if (n1 < N_NODES) dinv[n1] = hist[t + 256] ? rsqrtf((float)hist[t + 256]) : 0.0f;
}

__global__ __launch_bounds__(256) void binD2(const int2* __restrict__ dbinned,
                                             const int* __restrict__ offs,
                                             const float* __restrict__ dinv,
                                             int* __restrict__ cnt,
                                             int* __restrict__ endp,
                                             int2* __restrict__ csr) {
    __shared__ int hist[512];
    __shared__ int lcur[512];
    int t = threadIdx.x;
    hist[t] = 0; hist[t + 256] = 0;
    __syncthreads();
    int b = blockIdx.x;
    int E1 = offs[NBINS * NBLK];
    int start = offs[(NBINS + b) * NBLK] - E1;
    int end = (b == NBINS - 1) ? E1 : offs[(NBINS + b + 1) * NBLK] - E1;
    for (int i = start + t; i < end; i += 256)
        atomicAdd(&hist[dbinned[i].y - (b << 9)], 1);
    __syncthreads();
    int o0 = hist[t], o1 = hist[t + 256];
    for (int off = 1; off < 512; off <<= 1) {
        int v0 = (t >= off) ? hist[t - off] : 0;
        int v1 = (t + 256 >= off) ? hist[t + 256 - off] : 0;
        __syncthreads();
        hist[t] += v0; hist[t + 256] += v1;
        __syncthreads();
    }
    int e0 = hist[t] - o0, e1 = hist[t + 256] - o1;
    lcur[t] = start + e0;
    lcur[t + 256] = start + e1;
    int n0 = (b << 9) + t, n1 = n0 + 256;
    if (n0 < N_NODES) { cnt[n0] = o0; endp[n0] = start + e0 + o0; }
    if (n1 < N_NODES) { cnt[n1] = o1; endp[n1] = start + e1 + o1; }
    __syncthreads();
    for (int i = start + t; i < end; i += 256) {
        int2 r = dbinned[i];
        int slot = atomicAdd(&lcur[r.y - (b << 9)], 1);
        float nrm = -dinv[r.x] * dinv[r.y];
        csr[slot] = make_int2(r.x, __float_as_int(nrm));
    }
}

// emb f32 -> bf16 (RNE), vectorized
__global__ __launch_bounds__(256) void embcvt(const float* __restrict__ in,
                                              ushort* __restrict__ out) {
    int i = (blockIdx.x * 256 + threadIdx.x) * 4;
    float4 v = *(const float4*)(in + i);
    ushort4 o;
    o.x = f2bf(v.x); o.y = f2bf(v.y); o.z = f2bf(v.z); o.w = f2bf(v.w);
    *(ushort4*)(out + i) = o;
}

// Fused layer: 16 nodes/wave aggregation (bf16 gather, f32 acc) + MFMA GEMM.
// A = [x | Tx1] 16x128 bf16 staged in LDS; B = [W0;W1] 128x64 bf16 pre-packed
// into fragment layout per block; C = 16x64 f32 via mfma_f32_16x16x32_bf16.
#define NPW 16
#define WPB 8
#define NPB (NPW * WPB)                       // 128
#define LB2 ((N_NODES + NPB - 1) / NPB)       // 782

__global__ __launch_bounds__(512, 5) void cheb_layer(const ushort* __restrict__ x,
                                                     const int2* __restrict__ csr,
                                                     const int* __restrict__ endp,
                                                     const int* __restrict__ cnt,
                                                     const float* __restrict__ W0,
                                                     const float* __restrict__ W1,
                                                     const float* __restrict__ bias,
                                                     ushort* __restrict__ out_bf,
                                                     float* __restrict__ out_f32,
                                                     int last) {
    __shared__ ushort sFB[16 * 64 * 8];   // 16 KB: B-fragments [f=kt*4+nt][lane][j]
    __shared__ ushort sA[WPB][16][136];   // 34 KB: A rows (pad 128->136 vs bank aliasing)

    int t = threadIdx.x;
    // pack B = [W0;W1] into MFMA B-fragment layout (coalesced f32 reads)
    for (int i = t; i < 128 * 64; i += 512) {
        int k = i >> 6, n = i & 63;
        float v = (k < 64) ? W0[k * 64 + n] : W1[(k - 64) * 64 + n];
        int kt = k >> 5, jj = k & 31;
        int f = kt * 4 + (n >> 4);
        int L = ((jj >> 3) << 4) | (n & 15);
        sFB[(f * 64 + L) * 8 + (jj & 7)] = f2bf(v);
    }
    __syncthreads();

    int lane = t & 63, wid = t >> 6;
    int c = lane & 15, q = lane >> 4;
    int nb = blockIdx.x * NPB + wid * NPW;

    int nend = 0, ncnt = 0;
    if (lane < NPW && nb + lane < N_NODES) {
        nend = endp[nb + lane];
        ncnt = cnt[nb + lane];
    }

    // ---- aggregate 16 nodes, stage A ----
    for (int g = 0; g < NPW; ++g) {
        int node = nb + g;
        int cn = __builtin_amdgcn_readlane(ncnt, g);
        int eend = __builtin_amdgcn_readlane(nend, g);
        int e = eend - cn;
        ushort xb = (node < N_NODES) ? x[(size_t)node * NF + lane] : (ushort)0;
        float a0 = 0, a1 = 0, a2 = 0, a3 = 0, a4 = 0, a5 = 0, a6 = 0, a7 = 0;
        for (; e + 8 <= eend; e += 8) {
            int2 p0 = csr[e + 0], p1 = csr[e + 1], p2 = csr[e + 2], p3 = csr[e + 3];
            int2 p4 = csr[e + 4], p5 = csr[e + 5], p6 = csr[e + 6], p7 = csr[e + 7];
            a0 = fmaf(__int_as_float(p0.y), bf2f(x[(size_t)p0.x * NF + lane]), a0);
            a1 = fmaf(__int_as_float(p1.y), bf2f(x[(size_t)p1.x * NF + lane]), a1);
            a2 = fmaf(__int_as_float(p2.y), bf2f(x[(size_t)p2.x * NF + lane]), a2);
            a3 = fmaf(__int_as_float(p3.y), bf2f(x[(size_t)p3.x * NF + lane]), a3);
            a4 = fmaf(__int_as_float(p4.y), bf2f(x[(size_t)p4.x * NF + lane]), a4);
            a5 = fmaf(__int_as_float(p5.y), bf2f(x[(size_t)p5.x * NF + lane]), a5);
            a6 = fmaf(__int_as_float(p6.y), bf2f(x[(size_t)p6.x * NF + lane]), a6);
            a7 = fmaf(__int_as_float(p7.y), bf2f(x[(size_t)p7.x * NF + lane]), a7);
        }
        if (e + 4 <= eend) {
            int2 p0 = csr[e + 0], p1 = csr[e + 1], p2 = csr[e + 2], p3 = csr[e + 3];
            a0 = fmaf(__int_as_float(p0.y), bf2f(x[(size_t)p0.x * NF + lane]), a0);
            a1 = fmaf(__int_as_float(p1.y), bf2f(x[(size_t)p1.x * NF + lane]), a1);
            a2 = fmaf(__int_as_float(p2.y), bf2f(x[(size_t)p2.x * NF + lane]), a2);
            a3 = fmaf(__int_as_float(p3.y), bf2f(x[(size_t)p3.x * NF + lane]), a3);
            e += 4;
        }
        if (e + 2 <= eend) {
            int2 p0 = csr[e + 0], p1 = csr[e + 1];
            a0 = fmaf(__int_as_float(p0.y), bf2f(x[(size_t)p0.x * NF + lane]), a0);
            a1 = fmaf(__int_as_float(p1.y), bf2f(x[(size_t)p1.x * NF + lane]), a1);
            e += 2;
        }
        if (e < eend) {
            int2 p0 = csr[e];
            a0 = fmaf(__int_as_float(p0.y), bf2f(x[(size_t)p0.x * NF + lane]), a0);
        }
        float acc = ((a0 + a1) + (a2 + a3)) + ((a4 + a5) + (a6 + a7));
        sA[wid][g][lane] = xb;
        sA[wid][g][64 + lane] = f2bf(acc);
    }
    __builtin_amdgcn_wave_barrier();

    // ---- MFMA: C[16 nodes x 64 feats] = A[16x128] * B[128x64] + bias ----
    float4v C[4];
#pragma unroll
    for (int nt = 0; nt < 4; ++nt) {
        float b = bias[nt * 16 + c];
        C[nt] = (float4v){b, b, b, b};
    }
#pragma unroll
    for (int kt = 0; kt < 4; ++kt) {
        short8 af = *(const short8*)&sA[wid][c][kt * 32 + q * 8];
#pragma unroll
        for (int nt = 0; nt < 4; ++nt) {
            short8 bfr = *(const short8*)&sFB[((kt * 4 + nt) * 64 + lane) * 8];
            C[nt] = __builtin_amdgcn_mfma_f32_16x16x32_bf16(af, bfr, C[nt], 0, 0, 0);
        }
    }

    // ---- store: row m = q*4+i, col n = nt*16+c ----
#pragma unroll
    for (int nt = 0; nt < 4; ++nt) {
#pragma unroll
        for (int i = 0; i < 4; ++i) {
            int node = nb + q * 4 + i;
            if (node < N_NODES) {
                float v = C[nt][i];
                if (!last) {
                    v = fmaxf(v, 0.0f);
                    out_bf[(size_t)node * NF + nt * 16 + c] = f2bf(v);
                } else {
                    out_f32[(size_t)node * NF + nt * 16 + c] = v;
                }
            }
        }
    }
}

extern "C" void kernel_launch(void* const* d_in, const int* in_sizes, int n_in,
                              void* d_out, int out_size, void* d_ws, size_t ws_size,
                              hipStream_t stream) {
    const int* ei = (const int*)d_in[0];
    const int* row = ei;
    const int* col = ei + N_EDGES;
    const float* emb = (const float*)d_in[1];
    const float* W1_0 = (const float*)d_in[2];
    const float* W1_1 = (const float*)d_in[3];
    const float* b1 = (const float*)d_in[4];
    const float* W2_0 = (const float*)d_in[5];
    const float* W2_1 = (const float*)d_in[6];
    const float* b2 = (const float*)d_in[7];
    float* out = (float*)d_out;

    char* ws = (char*)d_ws;
    float* dinv = (float*)(ws + OFF_DINV);
    int* cnt = (int*)(ws + OFF_CNT);
    int* endp = (int*)(ws + OFF_ENDP);
    int* bsums = (int*)(ws + OFF_BSUMS);
    int2* csr = (int2*)(ws + OFF_CSR);
    char* scratch = ws + OFF_SCRATCH;
    int* sbinned = (int*)(scratch);
    int2* dbinned = (int2*)(scratch + 4800000);
    int* counts = (int*)(scratch + 14400000);
    int* offs = (int*)(scratch + 14800000);
    ushort* emb_bf = (ushort*)(scratch);              // after binD2
    ushort* h_bf = (ushort*)(scratch + 12800000);     // after binD2

    binA<<<NBLK, 256, 0, stream>>>(row, col, counts);
    scanA<<<SCAN_BLOCKS, 256, 0, stream>>>(counts, offs, bsums);
    scanB<<<1, 512, 0, stream>>>(bsums);
    scanC<<<SCAN_BLOCKS, 256, 0, stream>>>(offs, bsums);
    binC<<<NBLK, 256, 0, stream>>>(row, col, offs, sbinned, dbinned);
    binD1<<<NBINS, 256, 0, stream>>>(sbinned, offs, dinv);
    binD2<<<NBINS, 256, 0, stream>>>(dbinned, offs, dinv, cnt, endp, csr);
    embcvt<<<(N_NODES * NF) / 1024, 256, 0, stream>>>(emb, emb_bf);

    cheb_layer<<<LB2, 512, 0, stream>>>(emb_bf, csr, endp, cnt, W1_0, W1_1, b1, h_bf, nullptr, 0);
    cheb_layer<<<LB2, 512, 0, stream>>>(h_bf, csr, endp, cnt, W2_0, W2_1, b2, nullptr, out, 1);
}